// Round 6
// baseline (478.182 us; speedup 1.0000x reference)
//
#include <hip/hip_runtime.h>
#include <stdint.h>

// SeqAttention: B=4,H=8,M=1024,L=3200,D=128,HID=1024, ATTN_LIM=2048, RAMP=128
#define B_   4
#define H_   8
#define BH_  32
#define M_   1024
#define L_   3200
#define D_   128
#define HID_ 1024
#define NT64 50                 /* L/64 */
#define CAUSAL_K 2175           /* max_mem - M - 1 */
#define POS_OFF  1152           /* L - 2M */
#define SCALE 0.08838834764831845f /* 1/sqrt(128) */
#define NEGV (-3.0e38f)
#define NEGH (-1.0e38f)

typedef short  bf16x8 __attribute__((ext_vector_type(8)));
typedef float  f32x4  __attribute__((ext_vector_type(4)));

__device__ __forceinline__ unsigned short f2bf(float x) {
    union { float f; uint32_t u; } v; v.f = x;
    return (unsigned short)((v.u + 0x7FFFu + ((v.u >> 16) & 1u)) >> 16);
}
__device__ __forceinline__ float bf2f(unsigned short h) {
    union { uint32_t u; float f; } v; v.u = ((uint32_t)h) << 16; return v.f;
}
// truncating pack: low16 = bf16(lo), high16 = bf16(hi) — single v_perm_b32
__device__ __forceinline__ uint32_t pack_bf2(float lo, float hi) {
    union { float f; uint32_t u; } a, b; a.f = lo; b.f = hi;
    return __builtin_amdgcn_perm(b.u, a.u, 0x07060302u);
}

// ---- DPP 16-lane reductions: pure VALU, no LDS pipe ----
template <int CTRL>
__device__ __forceinline__ float dpp_movf(float x) {
    union { float f; int i; } u; u.f = x;
    u.i = __builtin_amdgcn_update_dpp(0, u.i, CTRL, 0xF, 0xF, true);
    return u.f;
}
__device__ __forceinline__ float row_max16(float x) {
    x = fmaxf(x, dpp_movf<0xB1>(x));
    x = fmaxf(x, dpp_movf<0x4E>(x));
    x = fmaxf(x, dpp_movf<0x141>(x));
    x = fmaxf(x, dpp_movf<0x140>(x));
    return x;
}
__device__ __forceinline__ float row_sum16(float x) {
    x += dpp_movf<0xB1>(x);
    x += dpp_movf<0x4E>(x);
    x += dpp_movf<0x141>(x);
    x += dpp_movf<0x140>(x);
    return x;
}

// ---- span (all blocks) + PET transpose (blocks < 256) fused ----
__global__ void span_pet_kernel(const float* __restrict__ hid,
                                const float* __restrict__ counter,
                                const float* __restrict__ sw,
                                const float* __restrict__ sb,
                                const float* __restrict__ PE,
                                float* __restrict__ r0_ws,
                                float* __restrict__ r0_out,
                                unsigned short* __restrict__ PET) {
    const int tid  = threadIdx.x;
    const int row  = blockIdx.x * 4 + (tid >> 6);   // one wave per (b,l)
    const int lane = tid & 63;
    const float* h = hid + (size_t)row * HID_;
    float acc = 0.f;
#pragma unroll
    for (int it = 0; it < 4; ++it) {
        const int k = it * 256 + lane * 4;
        const float4 a = *(const float4*)(h + k);
        const float4 w = *(const float4*)(sw + k);
        acc += a.x*w.x + a.y*w.y + a.z*w.z + a.w*w.w;
    }
#pragma unroll
    for (int off = 32; off; off >>= 1) acc += __shfl_down(acc, off);
    if (lane == 0) {
        const float x  = acc * (1.0f/16.0f) + sb[0];
        const float ms = 2048.0f / (1.0f + __expf(-x));
        const float r0 = ms - counter[row];
        r0_ws[row]  = r0;
        r0_out[row] = r0;
    }
    // fused PET transpose
    if (PET != nullptr && blockIdx.x < M_ / 4) {
        const int c = blockIdx.x * 4 + (tid >> 6);
        const int e = tid & 63;
        const float lo = PE[(2*e)   * M_ + c];
        const float hi = PE[(2*e+1) * M_ + c];
        ((uint32_t*)PET)[c * 64 + e] = pack_bf2(lo, hi);
    }
}

// ---- prep: tilemax (blocks 0..49, 4 tiles each) + aux_loss (blocks 50..53) ----
__global__ void prep_kernel(const float* __restrict__ r0_ws,
                            float* __restrict__ tmax,
                            float* __restrict__ aux_out) {
    __shared__ float red[256];
    const int bid = blockIdx.x;
    const int tid = threadIdx.x;
    if (bid < 50) {
        const int wave = tid >> 6, lane = tid & 63;
        const int t = bid * 4 + wave;                 // 0..199
        float v = r0_ws[t * 64 + lane];
#pragma unroll
        for (int off = 32; off; off >>= 1) v = fmaxf(v, __shfl_down(v, off));
        if (lane == 0) tmax[t] = v;
    } else {
        const int b = bid - 50;
        float s = 0.f;
        for (int l = tid; l < L_; l += 256) {
            const float r = r0_ws[b * L_ + l];
            const int fl = (int)floorf(r);
            int mlo = fl + 1;   if (mlo < 0) mlo = 0;
            int mhi = fl + 128; if (mhi > M_ - 1) mhi = M_ - 1;
            const int n = mhi - mlo + 1;
            if (n > 0) s += (float)n * r - 0.5f * (float)(mlo + mhi) * (float)n;
        }
        red[tid] = s; __syncthreads();
        for (int st = 128; st; st >>= 1) {
            if (tid < st) red[tid] += red[tid + st];
            __syncthreads();
        }
        if (tid == 0) aux_out[b] = red[0] * (1.0f/128.0f) * (1.0f/1024.0f) * 1e-6f;
    }
}

// ================= optimized flash attention (r4 structure + polish) =========
#define KS_STR 136   /* 128 + 8 (bf16 elems); 8*odd for b128 bank spread */
#define VT_STR 72    /* 64 + 8 */
#define PE_STR 136
#define P_STR  72
#define T_STR  72

__global__ void __launch_bounds__(256, 2)
attn_kernel(const float* __restrict__ Q, const float* __restrict__ K,
            const float* __restrict__ V, const unsigned short* __restrict__ PET,
            const float* __restrict__ r0g, const float* __restrict__ tmax,
            float* __restrict__ out) {
    __shared__ short Ks[64 * KS_STR];        // K tile [l][d]
    __shared__ short Vt[128 * VT_STR];       // V tile transposed [d][l]
    __shared__ short PEs[64 * PE_STR];       // PE^T tile [c][d]
    __shared__ short Tb[2][64 * T_STR];      // rolling Q@PE tiles (wave-private rows)
    __shared__ short Pb[64 * P_STR];         // P tile [m][l] (wave-private rows)

    // XCD-contiguous remap (bijective, 512 = 8*64): each XCD gets 4 whole bh's
    // x all 16 i-blocks -> per-XCD K/V working set ~5.6MB, near L2-resident.
    const int flat = (int)blockIdx.x + 16 * (int)blockIdx.y;
    const int work = (flat & 7) * 64 + (flat >> 3);
    const int bh  = work >> 4;
    const int bxx = work & 15;
    const int b  = bh >> 3;
    const int i0 = bxx << 6;
    const int tid  = threadIdx.x;
    const int wave = tid >> 6;
    const int lane = tid & 63;
    const int lq   = lane & 15;
    const int quad = lane >> 4;
    const int lt_end = min(NT64, bxx + 35);   // causal bound

    // ---- live-tile bitmask: one ballot, no LDS, no barrier ----
    const float live_thresh = (float)(i0 - 128);
    unsigned long long live_mask;
    {
        const int sidx = (lane < NT64) ? lane : (NT64 - 1);
        const float tv = tmax[b * NT64 + sidx];
        live_mask = __ballot((lane < NT64) && (lane < lt_end) && (tv > live_thresh));
    }
    auto next_live = [&](int s) -> int {
        const unsigned long long m = live_mask >> s;   // s <= 50 < 64 always
        return m ? (s + __builtin_ctzll(m)) : lt_end;
    };

    // ---- prefetch registers (tile lt staged here before LDS write) ----
    float4 kp[8];
    float4 vpa[4], vpb[4];
    uint4  pep[4];
    float  rvp[4];            // per-lane r0 for cols nt*16+lq
    float  rv[4];             // current tile's r0 (copied at write_stage)

    auto issue_prefetch = [&](int plt) {
        const int l0p = plt << 6;
        const float* kb = K + ((size_t)bh * L_ + l0p) * D_;
        const float* vb = V + ((size_t)bh * L_ + l0p) * D_;
#pragma unroll
        for (int it = 0; it < 8; ++it) {
            const int f = it * 256 + tid;
            kp[it] = *(const float4*)(kb + (f >> 5) * D_ + (f & 31) * 4);
        }
        const int p2 = (tid & 31) * 2;
#pragma unroll
        for (int it = 0; it < 4; ++it) {
            const int c = it * 8 + (tid >> 5);
            vpa[it] = *(const float4*)(vb + (size_t)p2 * D_ + c * 4);
            vpb[it] = *(const float4*)(vb + (size_t)(p2 + 1) * D_ + c * 4);
        }
        const int c0p = l0p - i0 - POS_OFF;
#pragma unroll
        for (int it = 0; it < 4; ++it) {
            const int f = it * 256 + tid;
            const int cg = c0p + (f >> 4);
            if ((unsigned)cg < (unsigned)M_)
                pep[it] = *(const uint4*)(PET + (size_t)cg * D_ + (f & 15) * 8);
            else { pep[it].x = 0; pep[it].y = 0; pep[it].z = 0; pep[it].w = 0; }
        }
        const float* rb = r0g + b * L_ + l0p;
#pragma unroll
        for (int nt = 0; nt < 4; ++nt) rvp[nt] = rb[nt * 16 + lq];
    };

    auto write_stage = [&]() {
#pragma unroll
        for (int it = 0; it < 8; ++it) {
            const int f = it * 256 + tid;
            uint2 w;
            w.x = pack_bf2(kp[it].x, kp[it].y);
            w.y = pack_bf2(kp[it].z, kp[it].w);
            *(uint2*)&Ks[(f >> 5) * KS_STR + (f & 31) * 4] = w;
        }
        const int p2 = (tid & 31) * 2;
#pragma unroll
        for (int it = 0; it < 4; ++it) {
            const int c = it * 8 + (tid >> 5);
            const float* a = (const float*)&vpa[it];
            const float* bb = (const float*)&vpb[it];
#pragma unroll
            for (int j = 0; j < 4; ++j)
                *(uint32_t*)&Vt[(c * 4 + j) * VT_STR + p2] = pack_bf2(a[j], bb[j]);
        }
#pragma unroll
        for (int it = 0; it < 4; ++it) {
            const int f = it * 256 + tid;
            *(uint4*)&PEs[(f >> 4) * PE_STR + (f & 15) * 8] = pep[it];
        }
#pragma unroll
        for (int nt = 0; nt < 4; ++nt) rv[nt] = rvp[nt];
    };

    // ---- Q fragments, PRE-SCALED by 1/sqrt(D): both QK^T and Q@PE inherit the
    // scale through the shared fragment (reference scales their sum), so the
    // per-tile s*SCALE disappears from the serial mask path.
    int lt = next_live(0);
    if (lt < lt_end) issue_prefetch(lt);

    bf16x8 qfrag[4];
    {
        const float* qp = Q + ((size_t)bh * M_ + (i0 + wave * 16 + lq)) * D_;
#pragma unroll
        for (int kk = 0; kk < 4; ++kk) {
            const float4 q0 = *(const float4*)(qp + kk * 32 + quad * 8);
            const float4 q1 = *(const float4*)(qp + kk * 32 + quad * 8 + 4);
            union { bf16x8 v; uint32_t u[4]; } qq;
            qq.u[0] = pack_bf2(q0.x * SCALE, q0.y * SCALE);
            qq.u[1] = pack_bf2(q0.z * SCALE, q0.w * SCALE);
            qq.u[2] = pack_bf2(q1.x * SCALE, q1.y * SCALE);
            qq.u[3] = pack_bf2(q1.z * SCALE, q1.w * SCALE);
            qfrag[kk] = qq.v;
        }
    }

    // T = Q @ PE^T tile; nt groups whose c-range misses [0, M) are never read
    // by the mask phase -> skip their MFMAs (cbase is wave-uniform).
    auto computeT = [&](short* tb, int cbase) {
        __builtin_amdgcn_s_setprio(1);
#pragma unroll
        for (int nt = 0; nt < 4; ++nt) {
            const int cb0 = cbase + nt * 16;
            if (cb0 > M_ - 1 || cb0 + 15 < 0) continue;
            f32x4 acc = (f32x4){0.f, 0.f, 0.f, 0.f};
#pragma unroll
            for (int kk = 0; kk < 4; ++kk) {
                const bf16x8 bf = *(const bf16x8*)&PEs[(nt*16 + lq) * PE_STR + kk*32 + quad*8];
                acc = __builtin_amdgcn_mfma_f32_16x16x32_bf16(qfrag[kk], bf, acc, 0, 0, 0);
            }
#pragma unroll
            for (int r = 0; r < 4; ++r) {
                union { float f; uint32_t u; } t; t.f = acc[r];
                tb[(wave*16 + quad*4 + r) * T_STR + nt*16 + lq] = (short)(t.u >> 16);
            }
        }
        __builtin_amdgcn_s_setprio(0);
    };

    f32x4 oacc[8];
#pragma unroll
    for (int d = 0; d < 8; ++d) oacc[d] = (f32x4){0.f, 0.f, 0.f, 0.f};
    float mrun[4] = {NEGV, NEGV, NEGV, NEGV};
    float Zm[4]   = {0.f, 0.f, 0.f, 0.f};
    int tlo = 0, thi = 1;
    int prev_c0 = -(1 << 30);

    while (lt < lt_end) {
        const int l0 = lt << 6;
        const int c0 = l0 - i0 - POS_OFF;
        const bool need_pos = (c0 + 63 >= 0) && (c0 - 63 <= M_ - 1);
        const bool rolling  = need_pos && (prev_c0 == c0 - 64);

        __syncthreads();                       // sync0: prev LDS reads done; prefetch drained here
        write_stage();
        __syncthreads();                       // sync1: staging visible (no VMEM outstanding -> cheap)

        // issue NEXT tile's loads now — they overlap the whole compute phase
        const int ltn = next_live(lt + 1);
        if (ltn < lt_end) issue_prefetch(ltn);

        // S = Q @ K^T (pre-scaled)
        f32x4 sfrag[4];
        __builtin_amdgcn_s_setprio(1);
#pragma unroll
        for (int nt = 0; nt < 4; ++nt) {
            f32x4 acc = (f32x4){0.f, 0.f, 0.f, 0.f};
#pragma unroll
            for (int kk = 0; kk < 4; ++kk) {
                const bf16x8 bf = *(const bf16x8*)&Ks[(nt*16 + lq) * KS_STR + kk*32 + quad*8];
                acc = __builtin_amdgcn_mfma_f32_16x16x32_bf16(qfrag[kk], bf, acc, 0, 0, 0);
            }
            sfrag[nt] = acc;
        }
        __builtin_amdgcn_s_setprio(0);

        // rel-pos T tiles (Tb rows are wave-private: no barrier needed)
        if (need_pos) {
            if (rolling) {
                const int t = tlo; tlo = thi; thi = t;
                computeT(&Tb[thi][0], c0);
            } else {
                tlo = 0; thi = 1;
                computeT(&Tb[1][0], c0);
                // restage PEs with the low tile (head/gap only, ~once per block)
                uint4 lowp[4];
#pragma unroll
                for (int it = 0; it < 4; ++it) {
                    const int f = it * 256 + tid;
                    const int cg = (c0 - 64) + (f >> 4);
                    if ((unsigned)cg < (unsigned)M_)
                        lowp[it] = *(const uint4*)(PET + (size_t)cg * D_ + (f & 15) * 8);
                    else { lowp[it].x = 0; lowp[it].y = 0; lowp[it].z = 0; lowp[it].w = 0; }
                }
                __syncthreads();               // all waves done reading PEs (T-hi)
#pragma unroll
                for (int it = 0; it < 4; ++it) {
                    const int f = it * 256 + tid;
                    *(uint4*)&PEs[(f >> 4) * PE_STR + (f & 15) * 8] = lowp[it];
                }
                __syncthreads();
                computeT(&Tb[0][0], c0 - 64);
            }
            prev_c0 = c0;
        } else {
            prev_c0 = -(1 << 30);
        }

        // fused mask + online softmax with DEFER-MAX: when this 4-row group's
        // local max hasn't outgrown mrun by >8, keep the old max — skips the
        // nm/alpha work AND the oacc rescale (serial alpha->mul->PV chain).
        // P <= e^8 is bf16-safe; normalization cancels the scale.
#pragma unroll
        for (int r = 0; r < 4; ++r) {
            const int iq = i0 + wave*16 + quad*4 + r;
            const float fiq = (float)iq;
            float sv[4], ev[4];
#pragma unroll
            for (int nt = 0; nt < 4; ++nt) {
                const int l = l0 + nt*16 + lq;
                float s = sfrag[nt][r];
                const int c = l - iq - POS_OFF;
                if (need_pos && (unsigned)c < (unsigned)M_) {
                    const int cb = c - (c0 - 64);          // in [1,127]
                    const short* tbp = (cb & 64) ? &Tb[thi][0] : &Tb[tlo][0];
                    s += bf2f((unsigned short)tbp[(wave*16 + quad*4 + r) * T_STR + (cb & 63)]);
                }
                const float e = fminf(fmaxf((rv[nt] - fiq) * 0.0078125f + 1.0f, 0.f), 1.f);
                ev[nt] = e;
                const bool live = (l <= iq + CAUSAL_K) && (e > 0.f);
                sv[nt] = live ? s : NEGV;     // already scaled via qfrag
            }
            float lm = fmaxf(fmaxf(sv[0], sv[1]), fmaxf(sv[2], sv[3]));
            lm = row_max16(lm);
            float pmv[4], pmsum = 0.f;
            // wave-uniform branch over this 4-row group (one row per quad)
            const bool defer = __all((lm - mrun[r] <= 8.f) && (mrun[r] > NEGH));
            if (defer) {
                const float nm = mrun[r];      // unchanged; alpha == 1
#pragma unroll
                for (int nt = 0; nt < 4; ++nt) {
                    const float p = __expf(sv[nt] - nm);   // dead -> 0
                    const float pm = p * ev[nt];
                    pmsum += pm; pmv[nt] = pm;
                }
                pmsum = row_sum16(pmsum);
                Zm[r] += pmsum;
            } else {
                const float nm = fmaxf(mrun[r], lm);
                float alpha = 1.f;
                if (nm > NEGH) {
                    alpha = (mrun[r] > NEGH) ? __expf(mrun[r] - nm) : 0.f;
#pragma unroll
                    for (int nt = 0; nt < 4; ++nt) {
                        const float p = __expf(sv[nt] - nm);
                        const float pm = p * ev[nt];
                        pmsum += pm; pmv[nt] = pm;
                    }
                } else {
                    pmv[0] = pmv[1] = pmv[2] = pmv[3] = 0.f;
                }
                pmsum = row_sum16(pmsum);
                mrun[r] = nm;
                Zm[r] = Zm[r] * alpha + pmsum;
#pragma unroll
                for (int d = 0; d < 8; ++d) oacc[d][r] *= alpha;
            }
#pragma unroll
            for (int nt = 0; nt < 4; ++nt) {
                union { float f; uint32_t u; } t; t.f = pmv[nt];
                Pb[(wave*16 + quad*4 + r) * P_STR + nt*16 + lq] = (short)(t.u >> 16);
            }
        }
        // no barrier: Pb rows are wave-private (writer rows wave*16+quad*4+r,
        // reader rows wave*16+lq are the same 16-row strip)

        // O += P @ V
        __builtin_amdgcn_s_setprio(1);
#pragma unroll
        for (int kk = 0; kk < 2; ++kk) {
            const bf16x8 pf = *(const bf16x8*)&Pb[(wave*16 + lq) * P_STR + kk*32 + quad*8];
#pragma unroll
            for (int dt = 0; dt < 8; ++dt) {
                const bf16x8 vf = *(const bf16x8*)&Vt[(dt*16 + lq) * VT_STR + kk*32 + quad*8];
                oacc[dt] = __builtin_amdgcn_mfma_f32_16x16x32_bf16(pf, vf, oacc[dt], 0, 0, 0);
            }
        }
        __builtin_amdgcn_s_setprio(0);
        lt = ltn;
    }

    // epilogue: out = O / (Zm + 1e-8)
#pragma unroll
    for (int r = 0; r < 4; ++r) {
        const int iq = i0 + wave*16 + quad*4 + r;
        const float inv = 1.0f / (Zm[r] + 1e-8f);
        float* op = out + ((size_t)bh * M_ + iq) * D_;
#pragma unroll
        for (int dt = 0; dt < 8; ++dt)
            op[dt*16 + lq] = oacc[dt][r] * inv;
    }
}

// ================= fallback (only if ws too small for PET) =================
__global__ void __launch_bounds__(256, 2)
attn_fb_kernel(const float* __restrict__ Q, const float* __restrict__ K,
               const float* __restrict__ V, const float* __restrict__ PE,
               const float* __restrict__ r0g, const float* __restrict__ tmax,
               float* __restrict__ out) {
    __shared__ short Ks[64 * KS_STR];
    __shared__ short Vt[128 * VT_STR];
    __shared__ short PEP[64 * PE_STR];
    __shared__ short Tb[2][64 * T_STR];
    __shared__ float r0s[64];

    const int bh = blockIdx.y;
    const int b  = bh >> 3;
    const int i0 = blockIdx.x << 6;
    const int tid  = threadIdx.x;
    const int wave = tid >> 6;
    const int lane = tid & 63;
    const int lq   = lane & 15;
    const int quad = lane >> 4;

    bf16x8 qfrag[4];
    {
        const float* qp = Q + ((size_t)bh * M_ + (i0 + wave * 16 + lq)) * D_;
#pragma unroll
        for (int kk = 0; kk < 4; ++kk) {
            const float* p = qp + kk * 32 + quad * 8;
            bf16x8 f;
#pragma unroll
            for (int j = 0; j < 8; ++j) f[j] = (short)f2bf(p[j]);
            qfrag[kk] = f;
        }
    }

    f32x4 oacc[8];
#pragma unroll
    for (int d = 0; d < 8; ++d) oacc[d] = (f32x4){0.f, 0.f, 0.f, 0.f};
    float mrun[4] = {NEGV, NEGV, NEGV, NEGV};
    float Zr[4]   = {0.f, 0.f, 0.f, 0.f};
    float Zm[4]   = {0.f, 0.f, 0.f, 0.f};

    int tlo = 0, thi = 1;
    int prev_c0 = -100000;

    auto stagePE = [&](int cbase) {
#pragma unroll
        for (int it = 0; it < 8; ++it) {
            const int f4 = it * 256 + tid;
            const int d  = f4 >> 4;
            const int cl = (f4 & 15) << 2;
#pragma unroll
            for (int j = 0; j < 4; ++j) {
                const int cg = cbase + cl + j;
                const float v = (cg >= 0 && cg < M_) ? PE[d * M_ + cg] : 0.f;
                PEP[(cl + j) * PE_STR + d] = (short)f2bf(v);
            }
        }
    };
    auto computeT = [&](short* tb) {
#pragma unroll
        for (int nt = 0; nt < 4; ++nt) {
            f32x4 acc = (f32x4){0.f, 0.f, 0.f, 0.f};
#pragma unroll
            for (int kk = 0; kk < 4; ++kk) {
                const bf16x8 bf = *(const bf16x8*)&PEP[(nt*16 + lq) * PE_STR + kk*32 + quad*8];
                acc = __builtin_amdgcn_mfma_f32_16x16x32_bf16(qfrag[kk], bf, acc, 0, 0, 0);
            }
#pragma unroll
            for (int r = 0; r < 4; ++r)
                tb[(wave*16 + quad*4 + r) * T_STR + nt*16 + lq] = (short)f2bf(acc[r]);
        }
    };

    const int lt_end = min(NT64, (int)blockIdx.x + 35);
    for (int lt = 0; lt < lt_end; ++lt) {
        const int l0 = lt << 6;
        if (!(tmax[b * NT64 + lt] > (float)(i0 - 128))) continue;

        __syncthreads();
        {
            const float* kbase = K + ((size_t)bh * L_ + l0) * D_;
            const float* vbase = V + ((size_t)bh * L_ + l0) * D_;
#pragma unroll
            for (int it = 0; it < 8; ++it) {
                const int f4 = it * 256 + tid;
                const int row = f4 >> 5;
                const int ds  = (f4 & 31) << 2;
                const float4 kv = *(const float4*)(kbase + row * D_ + ds);
                uint2 pk;
                pk.x = (uint32_t)f2bf(kv.x) | ((uint32_t)f2bf(kv.y) << 16);
                pk.y = (uint32_t)f2bf(kv.z) | ((uint32_t)f2bf(kv.w) << 16);
                *(uint2*)&Ks[row * KS_STR + ds] = pk;
                const float4 vv = *(const float4*)(vbase + row * D_ + ds);
                Vt[(ds+0) * VT_STR + row] = (short)f2bf(vv.x);
                Vt[(ds+1) * VT_STR + row] = (short)f2bf(vv.y);
                Vt[(ds+2) * VT_STR + row] = (short)f2bf(vv.z);
                Vt[(ds+3) * VT_STR + row] = (short)f2bf(vv.w);
            }
            if (tid < 64) r0s[tid] = r0g[b * L_ + l0 + tid];
        }

        const int c0 = l0 - i0 - POS_OFF;
        const bool need_pos = (c0 + 63 >= 0) && (c0 - 63 <= M_ - 1);
        if (need_pos) {
            if (prev_c0 == c0 - 64) {
                const int t = tlo; tlo = thi; thi = t;
                stagePE(c0);
                __syncthreads();
                computeT(&Tb[thi][0]);
            } else {
                stagePE(c0 - 64);
                __syncthreads();
                computeT(&Tb[0][0]);
                __syncthreads();
                stagePE(c0);
                __syncthreads();
                computeT(&Tb[1][0]);
                tlo = 0; thi = 1;
            }
            prev_c0 = c0;
        } else {
            __syncthreads();
        }

        f32x4 sfrag[4];
#pragma unroll
        for (int nt = 0; nt < 4; ++nt) {
            f32x4 acc = (f32x4){0.f, 0.f, 0.f, 0.f};
#pragma unroll
            for (int kk = 0; kk < 4; ++kk) {
                const bf16x8 bf = *(const bf16x8*)&Ks[(nt*16 + lq) * KS_STR + kk*32 + quad*8];
                acc = __builtin_amdgcn_mfma_f32_16x16x32_bf16(qfrag[kk], bf, acc, 0, 0, 0);
            }
            sfrag[nt] = acc;
        }
        __syncthreads();

        float sv[4][4];
#pragma unroll
        for (int r = 0; r < 4; ++r) {
            const int iq = i0 + wave*16 + quad*4 + r;
#pragma unroll
            for (int nt = 0; nt < 4; ++nt) {
                const int l = l0 + nt*16 + lq;
                float s = sfrag[nt][r];
                const int c = l - iq - POS_OFF;
                if (c >= 0 && c < M_) {
                    const int cb = c - (c0 - 64);
                    const short* tbp = (cb & 64) ? &Tb[thi][0] : &Tb[tlo][0];
                    s += bf2f((unsigned short)tbp[(wave*16 + quad*4 + r) * T_STR + (cb & 63)]);
                }
                const float e = fminf(fmaxf((r0s[nt*16 + lq] - (float)iq) * 0.0078125f + 1.0f, 0.f), 1.f);
                const bool live = (l <= iq + CAUSAL_K) && (e > 0.f);
                sv[r][nt] = live ? s * SCALE : NEGV;
            }
        }

#pragma unroll
        for (int r = 0; r < 4; ++r) {
            float v = fmaxf(fmaxf(sv[r][0], sv[r][1]), fmaxf(sv[r][2], sv[r][3]));
            v = row_max16(v);
            const float nm = fmaxf(mrun[r], v);
            float alpha, pmv[4];
            float psum = 0.f, pmsum = 0.f;
            if (nm > NEGH) {
                alpha = (mrun[r] > NEGH) ? __expf(mrun[r] - nm) : 0.f;
                const int iq = i0 + wave*16 + quad*4 + r;
#pragma unroll
                for (int nt = 0; nt < 4; ++nt) {
                    const float p = __expf(sv[r][nt] - nm);
                    const float e = fminf(fmaxf((r0s[nt*16 + lq] - (float)iq) * 0.0078125f + 1.0f, 0.f), 1.f);
                    const float pm = p * e;
                    psum += p; pmsum += pm; pmv[nt] = pm;
                }
            } else {
                alpha = 1.f;
                pmv[0] = pmv[1] = pmv[2] = pmv[3] = 0.f;
            }
            psum  = row_sum16(psum);
            pmsum = row_sum16(pmsum);
            mrun[r] = nm;
            Zr[r] = Zr[r] * alpha + psum;
            Zm[r] = Zm[r] * alpha + pmsum;
#pragma unroll
            for (int d = 0; d < 8; ++d) oacc[d][r] *= alpha;
#pragma unroll
            for (int nt = 0; nt < 4; ++nt)
                PEP[(wave*16 + quad*4 + r) * P_STR + nt*16 + lq] = (short)f2bf(pmv[nt]);
        }
        __syncthreads();

#pragma unroll
        for (int kk = 0; kk < 2; ++kk) {
            const bf16x8 pf = *(const bf16x8*)&PEP[(wave*16 + lq) * P_STR + kk*32 + quad*8];
#pragma unroll
            for (int dt = 0; dt < 8; ++dt) {
                const bf16x8 vf = *(const bf16x8*)&Vt[(dt*16 + lq) * VT_STR + kk*32 + quad*8];
                oacc[dt] = __builtin_amdgcn_mfma_f32_16x16x32_bf16(pf, vf, oacc[dt], 0, 0, 0);
            }
        }
    }

#pragma unroll
    for (int r = 0; r < 4; ++r) {
        const int iq = i0 + wave*16 + quad*4 + r;
        const float inv = 1.0f / (Zm[r] + 1e-8f * Zr[r]);
        float* op = out + ((size_t)bh * M_ + iq) * D_;
#pragma unroll
        for (int dt = 0; dt < 8; ++dt)
            op[dt*16 + lq] = oacc[dt][r] * inv;
    }
}

extern "C" void kernel_launch(void* const* d_in, const int* in_sizes, int n_in,
                              void* d_out, int out_size, void* d_ws, size_t ws_size,
                              hipStream_t stream) {
    (void)in_sizes; (void)n_in; (void)out_size;
    const float* Q       = (const float*)d_in[0];
    const float* K       = (const float*)d_in[1];
    const float* V       = (const float*)d_in[2];
    const float* hid     = (const float*)d_in[3];
    const float* counter = (const float*)d_in[4];
    const float* pe      = (const float*)d_in[5];
    const float* sw      = (const float*)d_in[6];
    const float* sb      = (const float*)d_in[7];

    float* out    = (float*)d_out;
    float* aux    = out + (size_t)BH_ * M_ * D_;
    float* r0_out = aux + B_;

    float* r0_ws = (float*)d_ws;                         // 12800 floats
    float* tmax  = r0_ws + B_ * L_;                      // 200 floats
    unsigned short* PET = (unsigned short*)(r0_ws + 13056); // 1024*128 bf16, 16B-aligned
    const bool use_pet = ws_size >= (size_t)(13056 * 4 + M_ * D_ * 2);

    span_pet_kernel<<<(B_ * L_) / 4, 256, 0, stream>>>(
        hid, counter, sw, sb, pe, r0_ws, r0_out, use_pet ? PET : nullptr);
    prep_kernel<<<54, 256, 0, stream>>>(r0_ws, tmax, aux);
    if (use_pet) {
        attn_kernel<<<dim3(M_ / 64, BH_), 256, 0, stream>>>(Q, K, V, PET, r0_ws, tmax, out);
    } else {
        attn_fb_kernel<<<dim3(M_ / 64, BH_), 256, 0, stream>>>(Q, K, V, pe, r0_ws, tmax, out);
    }
}

// Round 7
// 232.540 us; speedup vs baseline: 2.0563x; 2.0563x over previous
//
#include <hip/hip_runtime.h>
#include <stdint.h>

// SeqAttention: B=4,H=8,M=1024,L=3200,D=128,HID=1024, ATTN_LIM=2048, RAMP=128
#define B_   4
#define H_   8
#define BH_  32
#define M_   1024
#define L_   3200
#define D_   128
#define HID_ 1024
#define NT64 50                 /* L/64 */
#define CAUSAL_K 2175           /* max_mem - M - 1 */
#define POS_OFF  1152           /* L - 2M */
#define SCALE 0.08838834764831845f /* 1/sqrt(128) */
#define NEGV (-3.0e38f)
#define NEGH (-1.0e38f)

typedef short  bf16x8 __attribute__((ext_vector_type(8)));
typedef float  f32x4  __attribute__((ext_vector_type(4)));

__device__ __forceinline__ unsigned short f2bf(float x) {
    union { float f; uint32_t u; } v; v.f = x;
    return (unsigned short)((v.u + 0x7FFFu + ((v.u >> 16) & 1u)) >> 16);
}
__device__ __forceinline__ float bf2f(unsigned short h) {
    union { uint32_t u; float f; } v; v.u = ((uint32_t)h) << 16; return v.f;
}
// truncating pack: low16 = bf16(lo), high16 = bf16(hi) — single v_perm_b32
__device__ __forceinline__ uint32_t pack_bf2(float lo, float hi) {
    union { float f; uint32_t u; } a, b; a.f = lo; b.f = hi;
    return __builtin_amdgcn_perm(b.u, a.u, 0x07060302u);
}

// ---- DPP 16-lane reductions: pure VALU, no LDS pipe ----
template <int CTRL>
__device__ __forceinline__ float dpp_movf(float x) {
    union { float f; int i; } u; u.f = x;
    u.i = __builtin_amdgcn_update_dpp(0, u.i, CTRL, 0xF, 0xF, true);
    return u.f;
}
__device__ __forceinline__ float row_max16(float x) {
    x = fmaxf(x, dpp_movf<0xB1>(x));
    x = fmaxf(x, dpp_movf<0x4E>(x));
    x = fmaxf(x, dpp_movf<0x141>(x));
    x = fmaxf(x, dpp_movf<0x140>(x));
    return x;
}
__device__ __forceinline__ float row_sum16(float x) {
    x += dpp_movf<0xB1>(x);
    x += dpp_movf<0x4E>(x);
    x += dpp_movf<0x141>(x);
    x += dpp_movf<0x140>(x);
    return x;
}

// ---- span (all blocks) + PET transpose (blocks < 256) fused ----
__global__ void span_pet_kernel(const float* __restrict__ hid,
                                const float* __restrict__ counter,
                                const float* __restrict__ sw,
                                const float* __restrict__ sb,
                                const float* __restrict__ PE,
                                float* __restrict__ r0_ws,
                                float* __restrict__ r0_out,
                                unsigned short* __restrict__ PET) {
    const int tid  = threadIdx.x;
    const int row  = blockIdx.x * 4 + (tid >> 6);   // one wave per (b,l)
    const int lane = tid & 63;
    const float* h = hid + (size_t)row * HID_;
    float acc = 0.f;
#pragma unroll
    for (int it = 0; it < 4; ++it) {
        const int k = it * 256 + lane * 4;
        const float4 a = *(const float4*)(h + k);
        const float4 w = *(const float4*)(sw + k);
        acc += a.x*w.x + a.y*w.y + a.z*w.z + a.w*w.w;
    }
#pragma unroll
    for (int off = 32; off; off >>= 1) acc += __shfl_down(acc, off);
    if (lane == 0) {
        const float x  = acc * (1.0f/16.0f) + sb[0];
        const float ms = 2048.0f / (1.0f + __expf(-x));
        const float r0 = ms - counter[row];
        r0_ws[row]  = r0;
        r0_out[row] = r0;
    }
    // fused PET transpose
    if (PET != nullptr && blockIdx.x < M_ / 4) {
        const int c = blockIdx.x * 4 + (tid >> 6);
        const int e = tid & 63;
        const float lo = PE[(2*e)   * M_ + c];
        const float hi = PE[(2*e+1) * M_ + c];
        ((uint32_t*)PET)[c * 64 + e] = pack_bf2(lo, hi);
    }
}

// ---- prep: tilemax (blocks 0..49, 4 tiles each) + aux_loss (blocks 50..53) ----
__global__ void prep_kernel(const float* __restrict__ r0_ws,
                            float* __restrict__ tmax,
                            float* __restrict__ aux_out) {
    __shared__ float red[256];
    const int bid = blockIdx.x;
    const int tid = threadIdx.x;
    if (bid < 50) {
        const int wave = tid >> 6, lane = tid & 63;
        const int t = bid * 4 + wave;                 // 0..199
        float v = r0_ws[t * 64 + lane];
#pragma unroll
        for (int off = 32; off; off >>= 1) v = fmaxf(v, __shfl_down(v, off));
        if (lane == 0) tmax[t] = v;
    } else {
        const int b = bid - 50;
        float s = 0.f;
        for (int l = tid; l < L_; l += 256) {
            const float r = r0_ws[b * L_ + l];
            const int fl = (int)floorf(r);
            int mlo = fl + 1;   if (mlo < 0) mlo = 0;
            int mhi = fl + 128; if (mhi > M_ - 1) mhi = M_ - 1;
            const int n = mhi - mlo + 1;
            if (n > 0) s += (float)n * r - 0.5f * (float)(mlo + mhi) * (float)n;
        }
        red[tid] = s; __syncthreads();
        for (int st = 128; st; st >>= 1) {
            if (tid < st) red[tid] += red[tid + st];
            __syncthreads();
        }
        if (tid == 0) aux_out[b] = red[0] * (1.0f/128.0f) * (1.0f/1024.0f) * 1e-6f;
    }
}

// ================= optimized flash attention (r4 structure + safe polish) ====
#define KS_STR 136   /* 128 + 8 (bf16 elems); 8*odd for b128 bank spread */
#define VT_STR 72    /* 64 + 8 */
#define PE_STR 136
#define P_STR  72
#define T_STR  72

__global__ void __launch_bounds__(256, 2)
attn_kernel(const float* __restrict__ Q, const float* __restrict__ K,
            const float* __restrict__ V, const unsigned short* __restrict__ PET,
            const float* __restrict__ r0g, const float* __restrict__ tmax,
            float* __restrict__ out) {
    __shared__ short Ks[64 * KS_STR];        // K tile [l][d]
    __shared__ short Vt[128 * VT_STR];       // V tile transposed [d][l]
    __shared__ short PEs[64 * PE_STR];       // PE^T tile [c][d]
    __shared__ short Tb[2][64 * T_STR];      // rolling Q@PE tiles (wave-private rows)
    __shared__ short Pb[64 * P_STR];         // P tile [m][l] (wave-private rows)

    // XCD-contiguous remap (bijective, 512 = 8*64): each XCD gets 4 whole bh's
    // x all 16 i-blocks -> per-XCD K/V working set ~5.6MB, near L2-resident.
    const int flat = (int)blockIdx.x + 16 * (int)blockIdx.y;
    const int work = (flat & 7) * 64 + (flat >> 3);
    const int bh  = work >> 4;
    const int bxx = work & 15;
    const int b  = bh >> 3;
    const int i0 = bxx << 6;
    const int tid  = threadIdx.x;
    const int wave = tid >> 6;
    const int lane = tid & 63;
    const int lq   = lane & 15;
    const int quad = lane >> 4;
    const int lt_end = min(NT64, bxx + 35);   // causal bound

    // ---- live-tile bitmask: one ballot, no LDS, no barrier ----
    const float live_thresh = (float)(i0 - 128);
    unsigned long long live_mask;
    {
        const int sidx = (lane < NT64) ? lane : (NT64 - 1);
        const float tv = tmax[b * NT64 + sidx];
        live_mask = __ballot((lane < NT64) && (lane < lt_end) && (tv > live_thresh));
    }
    auto next_live = [&](int s) -> int {
        const unsigned long long m = live_mask >> s;   // s <= 50 < 64 always
        return m ? (s + __builtin_ctzll(m)) : lt_end;
    };

    // ---- prefetch registers (tile lt staged here before LDS write) ----
    float4 kp[8];
    float4 vpa[4], vpb[4];
    uint4  pep[4];
    float  rvp[4];            // per-lane r0 for cols nt*16+lq
    float  rv[4];             // current tile's r0 (copied at write_stage)

    auto issue_prefetch = [&](int plt) {
        const int l0p = plt << 6;
        const float* kb = K + ((size_t)bh * L_ + l0p) * D_;
        const float* vb = V + ((size_t)bh * L_ + l0p) * D_;
#pragma unroll
        for (int it = 0; it < 8; ++it) {
            const int f = it * 256 + tid;
            kp[it] = *(const float4*)(kb + (f >> 5) * D_ + (f & 31) * 4);
        }
        const int p2 = (tid & 31) * 2;
#pragma unroll
        for (int it = 0; it < 4; ++it) {
            const int c = it * 8 + (tid >> 5);
            vpa[it] = *(const float4*)(vb + (size_t)p2 * D_ + c * 4);
            vpb[it] = *(const float4*)(vb + (size_t)(p2 + 1) * D_ + c * 4);
        }
        const int c0p = l0p - i0 - POS_OFF;
#pragma unroll
        for (int it = 0; it < 4; ++it) {
            const int f = it * 256 + tid;
            const int cg = c0p + (f >> 4);
            if ((unsigned)cg < (unsigned)M_)
                pep[it] = *(const uint4*)(PET + (size_t)cg * D_ + (f & 15) * 8);
            else { pep[it].x = 0; pep[it].y = 0; pep[it].z = 0; pep[it].w = 0; }
        }
        const float* rb = r0g + b * L_ + l0p;
#pragma unroll
        for (int nt = 0; nt < 4; ++nt) rvp[nt] = rb[nt * 16 + lq];
    };

    auto write_stage = [&]() {
#pragma unroll
        for (int it = 0; it < 8; ++it) {
            const int f = it * 256 + tid;
            uint2 w;
            w.x = pack_bf2(kp[it].x, kp[it].y);
            w.y = pack_bf2(kp[it].z, kp[it].w);
            *(uint2*)&Ks[(f >> 5) * KS_STR + (f & 31) * 4] = w;
        }
        const int p2 = (tid & 31) * 2;
#pragma unroll
        for (int it = 0; it < 4; ++it) {
            const int c = it * 8 + (tid >> 5);
            const float* a = (const float*)&vpa[it];
            const float* bb = (const float*)&vpb[it];
#pragma unroll
            for (int j = 0; j < 4; ++j)
                *(uint32_t*)&Vt[(c * 4 + j) * VT_STR + p2] = pack_bf2(a[j], bb[j]);
        }
#pragma unroll
        for (int it = 0; it < 4; ++it) {
            const int f = it * 256 + tid;
            *(uint4*)&PEs[(f >> 4) * PE_STR + (f & 15) * 8] = pep[it];
        }
#pragma unroll
        for (int nt = 0; nt < 4; ++nt) rv[nt] = rvp[nt];
    };

    // ---- Q fragments, PRE-SCALED by 1/sqrt(D): both QK^T and Q@PE inherit the
    // scale through the shared fragment (reference scales their sum), so the
    // per-tile s*SCALE disappears from the serial mask path.
    int lt = next_live(0);
    if (lt < lt_end) issue_prefetch(lt);

    bf16x8 qfrag[4];
    {
        const float* qp = Q + ((size_t)bh * M_ + (i0 + wave * 16 + lq)) * D_;
#pragma unroll
        for (int kk = 0; kk < 4; ++kk) {
            const float4 q0 = *(const float4*)(qp + kk * 32 + quad * 8);
            const float4 q1 = *(const float4*)(qp + kk * 32 + quad * 8 + 4);
            union { bf16x8 v; uint32_t u[4]; } qq;
            qq.u[0] = pack_bf2(q0.x * SCALE, q0.y * SCALE);
            qq.u[1] = pack_bf2(q0.z * SCALE, q0.w * SCALE);
            qq.u[2] = pack_bf2(q1.x * SCALE, q1.y * SCALE);
            qq.u[3] = pack_bf2(q1.z * SCALE, q1.w * SCALE);
            qfrag[kk] = qq.v;
        }
    }

    // T = Q @ PE^T tile; nt groups whose c-range misses [0, M) are never read
    // by the mask phase -> skip their MFMAs (cbase is wave-uniform).
    auto computeT = [&](short* tb, int cbase) {
        __builtin_amdgcn_s_setprio(1);
#pragma unroll
        for (int nt = 0; nt < 4; ++nt) {
            const int cb0 = cbase + nt * 16;
            if (cb0 > M_ - 1 || cb0 + 15 < 0) continue;
            f32x4 acc = (f32x4){0.f, 0.f, 0.f, 0.f};
#pragma unroll
            for (int kk = 0; kk < 4; ++kk) {
                const bf16x8 bf = *(const bf16x8*)&PEs[(nt*16 + lq) * PE_STR + kk*32 + quad*8];
                acc = __builtin_amdgcn_mfma_f32_16x16x32_bf16(qfrag[kk], bf, acc, 0, 0, 0);
            }
#pragma unroll
            for (int r = 0; r < 4; ++r) {
                union { float f; uint32_t u; } t; t.f = acc[r];
                tb[(wave*16 + quad*4 + r) * T_STR + nt*16 + lq] = (short)(t.u >> 16);
            }
        }
        __builtin_amdgcn_s_setprio(0);
    };

    f32x4 oacc[8];
#pragma unroll
    for (int d = 0; d < 8; ++d) oacc[d] = (f32x4){0.f, 0.f, 0.f, 0.f};
    float mrun[4] = {NEGV, NEGV, NEGV, NEGV};
    float Zm[4]   = {0.f, 0.f, 0.f, 0.f};
    int tlo = 0, thi = 1;
    int prev_c0 = -(1 << 30);

    while (lt < lt_end) {
        const int l0 = lt << 6;
        const int c0 = l0 - i0 - POS_OFF;
        const bool need_pos = (c0 + 63 >= 0) && (c0 - 63 <= M_ - 1);
        const bool rolling  = need_pos && (prev_c0 == c0 - 64);

        __syncthreads();                       // sync0: prev LDS reads done; prefetch drained here
        write_stage();
        __syncthreads();                       // sync1: staging visible (no VMEM outstanding -> cheap)

        // issue NEXT tile's loads now — they overlap the whole compute phase
        const int ltn = next_live(lt + 1);
        if (ltn < lt_end) issue_prefetch(ltn);

        // S = Q @ K^T (pre-scaled)
        f32x4 sfrag[4];
        __builtin_amdgcn_s_setprio(1);
#pragma unroll
        for (int nt = 0; nt < 4; ++nt) {
            f32x4 acc = (f32x4){0.f, 0.f, 0.f, 0.f};
#pragma unroll
            for (int kk = 0; kk < 4; ++kk) {
                const bf16x8 bf = *(const bf16x8*)&Ks[(nt*16 + lq) * KS_STR + kk*32 + quad*8];
                acc = __builtin_amdgcn_mfma_f32_16x16x32_bf16(qfrag[kk], bf, acc, 0, 0, 0);
            }
            sfrag[nt] = acc;
        }
        __builtin_amdgcn_s_setprio(0);

        // rel-pos T tiles (Tb rows are wave-private: no barrier needed)
        if (need_pos) {
            if (rolling) {
                const int t = tlo; tlo = thi; thi = t;
                computeT(&Tb[thi][0], c0);
            } else {
                tlo = 0; thi = 1;
                computeT(&Tb[1][0], c0);
                // restage PEs with the low tile (head/gap only, ~once per block)
                uint4 lowp[4];
#pragma unroll
                for (int it = 0; it < 4; ++it) {
                    const int f = it * 256 + tid;
                    const int cg = (c0 - 64) + (f >> 4);
                    if ((unsigned)cg < (unsigned)M_)
                        lowp[it] = *(const uint4*)(PET + (size_t)cg * D_ + (f & 15) * 8);
                    else { lowp[it].x = 0; lowp[it].y = 0; lowp[it].z = 0; lowp[it].w = 0; }
                }
                __syncthreads();               // all waves done reading PEs (T-hi)
#pragma unroll
                for (int it = 0; it < 4; ++it) {
                    const int f = it * 256 + tid;
                    *(uint4*)&PEs[(f >> 4) * PE_STR + (f & 15) * 8] = lowp[it];
                }
                __syncthreads();
                computeT(&Tb[0][0], c0 - 64);
            }
            prev_c0 = c0;
        } else {
            prev_c0 = -(1 << 30);
        }

        // fused mask + online softmax, single path (r4-proven; no defer-max:
        // the duplicated-body variant spilled — this kernel sits exactly at
        // the 128-VGPR boundary and tolerates no second live code path)
#pragma unroll
        for (int r = 0; r < 4; ++r) {
            const int iq = i0 + wave*16 + quad*4 + r;
            const float fiq = (float)iq;
            float sv[4], ev[4];
#pragma unroll
            for (int nt = 0; nt < 4; ++nt) {
                const int l = l0 + nt*16 + lq;
                float s = sfrag[nt][r];
                const int c = l - iq - POS_OFF;
                if (need_pos && (unsigned)c < (unsigned)M_) {
                    const int cb = c - (c0 - 64);          // in [1,127]
                    const short* tbp = (cb & 64) ? &Tb[thi][0] : &Tb[tlo][0];
                    s += bf2f((unsigned short)tbp[(wave*16 + quad*4 + r) * T_STR + (cb & 63)]);
                }
                const float e = fminf(fmaxf((rv[nt] - fiq) * 0.0078125f + 1.0f, 0.f), 1.f);
                ev[nt] = e;
                const bool live = (l <= iq + CAUSAL_K) && (e > 0.f);
                sv[nt] = live ? s : NEGV;     // already scaled via qfrag
            }
            float v = fmaxf(fmaxf(sv[0], sv[1]), fmaxf(sv[2], sv[3]));
            v = row_max16(v);
            const float nm = fmaxf(mrun[r], v);
            float alpha = 1.f, pmsum = 0.f, pmv[4];
            if (nm > NEGH) {
                alpha = (mrun[r] > NEGH) ? __expf(mrun[r] - nm) : 0.f;
#pragma unroll
                for (int nt = 0; nt < 4; ++nt) {
                    const float p = __expf(sv[nt] - nm);   // dead -> 0
                    const float pm = p * ev[nt];
                    pmsum += pm; pmv[nt] = pm;
                }
            } else {
                pmv[0] = pmv[1] = pmv[2] = pmv[3] = 0.f;
            }
            pmsum = row_sum16(pmsum);
            mrun[r] = nm;
            Zm[r] = Zm[r] * alpha + pmsum;
#pragma unroll
            for (int d = 0; d < 8; ++d) oacc[d][r] *= alpha;
#pragma unroll
            for (int nt = 0; nt < 4; ++nt) {
                union { float f; uint32_t u; } t; t.f = pmv[nt];
                Pb[(wave*16 + quad*4 + r) * P_STR + nt*16 + lq] = (short)(t.u >> 16);
            }
        }
        // no barrier: Pb rows are wave-private (writer rows wave*16+quad*4+r,
        // reader rows wave*16+lq are the same 16-row strip)

        // O += P @ V
        __builtin_amdgcn_s_setprio(1);
#pragma unroll
        for (int kk = 0; kk < 2; ++kk) {
            const bf16x8 pf = *(const bf16x8*)&Pb[(wave*16 + lq) * P_STR + kk*32 + quad*8];
#pragma unroll
            for (int dt = 0; dt < 8; ++dt) {
                const bf16x8 vf = *(const bf16x8*)&Vt[(dt*16 + lq) * VT_STR + kk*32 + quad*8];
                oacc[dt] = __builtin_amdgcn_mfma_f32_16x16x32_bf16(pf, vf, oacc[dt], 0, 0, 0);
            }
        }
        __builtin_amdgcn_s_setprio(0);
        lt = ltn;
    }

    // epilogue: out = O / (Zm + 1e-8)
#pragma unroll
    for (int r = 0; r < 4; ++r) {
        const int iq = i0 + wave*16 + quad*4 + r;
        const float inv = 1.0f / (Zm[r] + 1e-8f);
        float* op = out + ((size_t)bh * M_ + iq) * D_;
#pragma unroll
        for (int dt = 0; dt < 8; ++dt)
            op[dt*16 + lq] = oacc[dt][r] * inv;
    }
}

// ================= fallback (only if ws too small for PET) =================
__global__ void __launch_bounds__(256, 2)
attn_fb_kernel(const float* __restrict__ Q, const float* __restrict__ K,
               const float* __restrict__ V, const float* __restrict__ PE,
               const float* __restrict__ r0g, const float* __restrict__ tmax,
               float* __restrict__ out) {
    __shared__ short Ks[64 * KS_STR];
    __shared__ short Vt[128 * VT_STR];
    __shared__ short PEP[64 * PE_STR];
    __shared__ short Tb[2][64 * T_STR];
    __shared__ float r0s[64];

    const int bh = blockIdx.y;
    const int b  = bh >> 3;
    const int i0 = blockIdx.x << 6;
    const int tid  = threadIdx.x;
    const int wave = tid >> 6;
    const int lane = tid & 63;
    const int lq   = lane & 15;
    const int quad = lane >> 4;

    bf16x8 qfrag[4];
    {
        const float* qp = Q + ((size_t)bh * M_ + (i0 + wave * 16 + lq)) * D_;
#pragma unroll
        for (int kk = 0; kk < 4; ++kk) {
            const float* p = qp + kk * 32 + quad * 8;
            bf16x8 f;
#pragma unroll
            for (int j = 0; j < 8; ++j) f[j] = (short)f2bf(p[j]);
            qfrag[kk] = f;
        }
    }

    f32x4 oacc[8];
#pragma unroll
    for (int d = 0; d < 8; ++d) oacc[d] = (f32x4){0.f, 0.f, 0.f, 0.f};
    float mrun[4] = {NEGV, NEGV, NEGV, NEGV};
    float Zr[4]   = {0.f, 0.f, 0.f, 0.f};
    float Zm[4]   = {0.f, 0.f, 0.f, 0.f};

    int tlo = 0, thi = 1;
    int prev_c0 = -100000;

    auto stagePE = [&](int cbase) {
#pragma unroll
        for (int it = 0; it < 8; ++it) {
            const int f4 = it * 256 + tid;
            const int d  = f4 >> 4;
            const int cl = (f4 & 15) << 2;
#pragma unroll
            for (int j = 0; j < 4; ++j) {
                const int cg = cbase + cl + j;
                const float v = (cg >= 0 && cg < M_) ? PE[d * M_ + cg] : 0.f;
                PEP[(cl + j) * PE_STR + d] = (short)f2bf(v);
            }
        }
    };
    auto computeT = [&](short* tb) {
#pragma unroll
        for (int nt = 0; nt < 4; ++nt) {
            f32x4 acc = (f32x4){0.f, 0.f, 0.f, 0.f};
#pragma unroll
            for (int kk = 0; kk < 4; ++kk) {
                const bf16x8 bf = *(const bf16x8*)&PEP[(nt*16 + lq) * PE_STR + kk*32 + quad*8];
                acc = __builtin_amdgcn_mfma_f32_16x16x32_bf16(qfrag[kk], bf, acc, 0, 0, 0);
            }
#pragma unroll
            for (int r = 0; r < 4; ++r)
                tb[(wave*16 + quad*4 + r) * T_STR + nt*16 + lq] = (short)f2bf(acc[r]);
        }
    };

    const int lt_end = min(NT64, (int)blockIdx.x + 35);
    for (int lt = 0; lt < lt_end; ++lt) {
        const int l0 = lt << 6;
        if (!(tmax[b * NT64 + lt] > (float)(i0 - 128))) continue;

        __syncthreads();
        {
            const float* kbase = K + ((size_t)bh * L_ + l0) * D_;
            const float* vbase = V + ((size_t)bh * L_ + l0) * D_;
#pragma unroll
            for (int it = 0; it < 8; ++it) {
                const int f4 = it * 256 + tid;
                const int row = f4 >> 5;
                const int ds  = (f4 & 31) << 2;
                const float4 kv = *(const float4*)(kbase + row * D_ + ds);
                uint2 pk;
                pk.x = (uint32_t)f2bf(kv.x) | ((uint32_t)f2bf(kv.y) << 16);
                pk.y = (uint32_t)f2bf(kv.z) | ((uint32_t)f2bf(kv.w) << 16);
                *(uint2*)&Ks[row * KS_STR + ds] = pk;
                const float4 vv = *(const float4*)(vbase + row * D_ + ds);
                Vt[(ds+0) * VT_STR + row] = (short)f2bf(vv.x);
                Vt[(ds+1) * VT_STR + row] = (short)f2bf(vv.y);
                Vt[(ds+2) * VT_STR + row] = (short)f2bf(vv.z);
                Vt[(ds+3) * VT_STR + row] = (short)f2bf(vv.w);
            }
            if (tid < 64) r0s[tid] = r0g[b * L_ + l0 + tid];
        }

        const int c0 = l0 - i0 - POS_OFF;
        const bool need_pos = (c0 + 63 >= 0) && (c0 - 63 <= M_ - 1);
        if (need_pos) {
            if (prev_c0 == c0 - 64) {
                const int t = tlo; tlo = thi; thi = t;
                stagePE(c0);
                __syncthreads();
                computeT(&Tb[thi][0]);
            } else {
                stagePE(c0 - 64);
                __syncthreads();
                computeT(&Tb[0][0]);
                __syncthreads();
                stagePE(c0);
                __syncthreads();
                computeT(&Tb[1][0]);
                tlo = 0; thi = 1;
            }
            prev_c0 = c0;
        } else {
            __syncthreads();
        }

        f32x4 sfrag[4];
#pragma unroll
        for (int nt = 0; nt < 4; ++nt) {
            f32x4 acc = (f32x4){0.f, 0.f, 0.f, 0.f};
#pragma unroll
            for (int kk = 0; kk < 4; ++kk) {
                const bf16x8 bf = *(const bf16x8*)&Ks[(nt*16 + lq) * KS_STR + kk*32 + quad*8];
                acc = __builtin_amdgcn_mfma_f32_16x16x32_bf16(qfrag[kk], bf, acc, 0, 0, 0);
            }
            sfrag[nt] = acc;
        }
        __syncthreads();

        float sv[4][4];
#pragma unroll
        for (int r = 0; r < 4; ++r) {
            const int iq = i0 + wave*16 + quad*4 + r;
#pragma unroll
            for (int nt = 0; nt < 4; ++nt) {
                const int l = l0 + nt*16 + lq;
                float s = sfrag[nt][r];
                const int c = l - iq - POS_OFF;
                if (c >= 0 && c < M_) {
                    const int cb = c - (c0 - 64);
                    const short* tbp = (cb & 64) ? &Tb[thi][0] : &Tb[tlo][0];
                    s += bf2f((unsigned short)tbp[(wave*16 + quad*4 + r) * T_STR + (cb & 63)]);
                }
                const float e = fminf(fmaxf((r0s[nt*16 + lq] - (float)iq) * 0.0078125f + 1.0f, 0.f), 1.f);
                const bool live = (l <= iq + CAUSAL_K) && (e > 0.f);
                sv[r][nt] = live ? s * SCALE : NEGV;
            }
        }

#pragma unroll
        for (int r = 0; r < 4; ++r) {
            float v = fmaxf(fmaxf(sv[r][0], sv[r][1]), fmaxf(sv[r][2], sv[r][3]));
            v = row_max16(v);
            const float nm = fmaxf(mrun[r], v);
            float alpha, pmv[4];
            float psum = 0.f, pmsum = 0.f;
            if (nm > NEGH) {
                alpha = (mrun[r] > NEGH) ? __expf(mrun[r] - nm) : 0.f;
                const int iq = i0 + wave*16 + quad*4 + r;
#pragma unroll
                for (int nt = 0; nt < 4; ++nt) {
                    const float p = __expf(sv[r][nt] - nm);
                    const float e = fminf(fmaxf((r0s[nt*16 + lq] - (float)iq) * 0.0078125f + 1.0f, 0.f), 1.f);
                    const float pm = p * e;
                    psum += p; pmsum += pm; pmv[nt] = pm;
                }
            } else {
                alpha = 1.f;
                pmv[0] = pmv[1] = pmv[2] = pmv[3] = 0.f;
            }
            psum  = row_sum16(psum);
            pmsum = row_sum16(pmsum);
            mrun[r] = nm;
            Zr[r] = Zr[r] * alpha + psum;
            Zm[r] = Zm[r] * alpha + pmsum;
#pragma unroll
            for (int d = 0; d < 8; ++d) oacc[d][r] *= alpha;
#pragma unroll
            for (int nt = 0; nt < 4; ++nt)
                PEP[(wave*16 + quad*4 + r) * P_STR + nt*16 + lq] = (short)f2bf(pmv[nt]);
        }
        __syncthreads();

#pragma unroll
        for (int kk = 0; kk < 2; ++kk) {
            const bf16x8 pf = *(const bf16x8*)&PEP[(wave*16 + lq) * P_STR + kk*32 + quad*8];
#pragma unroll
            for (int dt = 0; dt < 8; ++dt) {
                const bf16x8 vf = *(const bf16x8*)&Vt[(dt*16 + lq) * VT_STR + kk*32 + quad*8];
                oacc[dt] = __builtin_amdgcn_mfma_f32_16x16x32_bf16(pf, vf, oacc[dt], 0, 0, 0);
            }
        }
    }

#pragma unroll
    for (int r = 0; r < 4; ++r) {
        const int iq = i0 + wave*16 + quad*4 + r;
        const float inv = 1.0f / (Zm[r] + 1e-8f * Zr[r]);
        float* op = out + ((size_t)bh * M_ + iq) * D_;
#pragma unroll
        for (int dt = 0; dt < 8; ++dt)
            op[dt*16 + lq] = oacc[dt][r] * inv;
    }
}

extern "C" void kernel_launch(void* const* d_in, const int* in_sizes, int n_in,
                              void* d_out, int out_size, void* d_ws, size_t ws_size,
                              hipStream_t stream) {
    (void)in_sizes; (void)n_in; (void)out_size;
    const float* Q       = (const float*)d_in[0];
    const float* K       = (const float*)d_in[1];
    const float* V       = (const float*)d_in[2];
    const float* hid     = (const float*)d_in[3];
    const float* counter = (const float*)d_in[4];
    const float* pe      = (const float*)d_in[5];
    const float* sw      = (const float*)d_in[6];
    const float* sb      = (const float*)d_in[7];

    float* out    = (float*)d_out;
    float* aux    = out + (size_t)BH_ * M_ * D_;
    float* r0_out = aux + B_;

    float* r0_ws = (float*)d_ws;                         // 12800 floats
    float* tmax  = r0_ws + B_ * L_;                      // 200 floats
    unsigned short* PET = (unsigned short*)(r0_ws + 13056); // 1024*128 bf16, 16B-aligned
    const bool use_pet = ws_size >= (size_t)(13056 * 4 + M_ * D_ * 2);

    span_pet_kernel<<<(B_ * L_) / 4, 256, 0, stream>>>(
        hid, counter, sw, sb, pe, r0_ws, r0_out, use_pet ? PET : nullptr);
    prep_kernel<<<54, 256, 0, stream>>>(r0_ws, tmax, aux);
    if (use_pet) {
        attn_kernel<<<dim3(M_ / 64, BH_), 256, 0, stream>>>(Q, K, V, PET, r0_ws, tmax, out);
    } else {
        attn_fb_kernel<<<dim3(M_ / 64, BH_), 256, 0, stream>>>(Q, K, V, pe, r0_ws, tmax, out);
    }
}

// Round 8
// 229.714 us; speedup vs baseline: 2.0816x; 1.0123x over previous
//
#include <hip/hip_runtime.h>
#include <stdint.h>

// SeqAttention: B=4,H=8,M=1024,L=3200,D=128,HID=1024, ATTN_LIM=2048, RAMP=128
#define B_   4
#define H_   8
#define BH_  32
#define M_   1024
#define L_   3200
#define D_   128
#define HID_ 1024
#define NT64 50                 /* L/64 */
#define CAUSAL_K 2175           /* max_mem - M - 1 */
#define POS_OFF  1152           /* L - 2M */
#define SCALE 0.08838834764831845f /* 1/sqrt(128) */
#define NEGV (-3.0e38f)
#define NEGH (-1.0e38f)

typedef short  bf16x8 __attribute__((ext_vector_type(8)));
typedef float  f32x4  __attribute__((ext_vector_type(4)));

__device__ __forceinline__ unsigned short f2bf(float x) {
    union { float f; uint32_t u; } v; v.f = x;
    return (unsigned short)((v.u + 0x7FFFu + ((v.u >> 16) & 1u)) >> 16);
}
__device__ __forceinline__ float bf2f(unsigned short h) {
    union { uint32_t u; float f; } v; v.u = ((uint32_t)h) << 16; return v.f;
}
// truncating pack: low16 = bf16(lo), high16 = bf16(hi) — single v_perm_b32
__device__ __forceinline__ uint32_t pack_bf2(float lo, float hi) {
    union { float f; uint32_t u; } a, b; a.f = lo; b.f = hi;
    return __builtin_amdgcn_perm(b.u, a.u, 0x07060302u);
}

// ---- DPP 16-lane reductions: pure VALU, no LDS pipe ----
template <int CTRL>
__device__ __forceinline__ float dpp_movf(float x) {
    union { float f; int i; } u; u.f = x;
    u.i = __builtin_amdgcn_update_dpp(0, u.i, CTRL, 0xF, 0xF, true);
    return u.f;
}
__device__ __forceinline__ float row_max16(float x) {
    x = fmaxf(x, dpp_movf<0xB1>(x));
    x = fmaxf(x, dpp_movf<0x4E>(x));
    x = fmaxf(x, dpp_movf<0x141>(x));
    x = fmaxf(x, dpp_movf<0x140>(x));
    return x;
}
__device__ __forceinline__ float row_sum16(float x) {
    x += dpp_movf<0xB1>(x);
    x += dpp_movf<0x4E>(x);
    x += dpp_movf<0x141>(x);
    x += dpp_movf<0x140>(x);
    return x;
}

// ---- span (all blocks) + PET transpose (blocks < 256) fused ----
__global__ void span_pet_kernel(const float* __restrict__ hid,
                                const float* __restrict__ counter,
                                const float* __restrict__ sw,
                                const float* __restrict__ sb,
                                const float* __restrict__ PE,
                                float* __restrict__ r0_ws,
                                float* __restrict__ r0_out,
                                unsigned short* __restrict__ PET) {
    const int tid  = threadIdx.x;
    const int row  = blockIdx.x * 4 + (tid >> 6);   // one wave per (b,l)
    const int lane = tid & 63;
    const float* h = hid + (size_t)row * HID_;
    float acc = 0.f;
#pragma unroll
    for (int it = 0; it < 4; ++it) {
        const int k = it * 256 + lane * 4;
        const float4 a = *(const float4*)(h + k);
        const float4 w = *(const float4*)(sw + k);
        acc += a.x*w.x + a.y*w.y + a.z*w.z + a.w*w.w;
    }
#pragma unroll
    for (int off = 32; off; off >>= 1) acc += __shfl_down(acc, off);
    if (lane == 0) {
        const float x  = acc * (1.0f/16.0f) + sb[0];
        const float ms = 2048.0f / (1.0f + __expf(-x));
        const float r0 = ms - counter[row];
        r0_ws[row]  = r0;
        r0_out[row] = r0;
    }
    // fused PET transpose
    if (PET != nullptr && blockIdx.x < M_ / 4) {
        const int c = blockIdx.x * 4 + (tid >> 6);
        const int e = tid & 63;
        const float lo = PE[(2*e)   * M_ + c];
        const float hi = PE[(2*e+1) * M_ + c];
        ((uint32_t*)PET)[c * 64 + e] = pack_bf2(lo, hi);
    }
}

// ---- prep: tilemax (blocks 0..49, 4 tiles each) + aux_loss (blocks 50..53) ----
__global__ void prep_kernel(const float* __restrict__ r0_ws,
                            float* __restrict__ tmax,
                            float* __restrict__ aux_out) {
    __shared__ float red[256];
    const int bid = blockIdx.x;
    const int tid = threadIdx.x;
    if (bid < 50) {
        const int wave = tid >> 6, lane = tid & 63;
        const int t = bid * 4 + wave;                 // 0..199
        float v = r0_ws[t * 64 + lane];
#pragma unroll
        for (int off = 32; off; off >>= 1) v = fmaxf(v, __shfl_down(v, off));
        if (lane == 0) tmax[t] = v;
    } else {
        const int b = bid - 50;
        float s = 0.f;
        for (int l = tid; l < L_; l += 256) {
            const float r = r0_ws[b * L_ + l];
            const int fl = (int)floorf(r);
            int mlo = fl + 1;   if (mlo < 0) mlo = 0;
            int mhi = fl + 128; if (mhi > M_ - 1) mhi = M_ - 1;
            const int n = mhi - mlo + 1;
            if (n > 0) s += (float)n * r - 0.5f * (float)(mlo + mhi) * (float)n;
        }
        red[tid] = s; __syncthreads();
        for (int st = 128; st; st >>= 1) {
            if (tid < st) red[tid] += red[tid + st];
            __syncthreads();
        }
        if (tid == 0) aux_out[b] = red[0] * (1.0f/128.0f) * (1.0f/1024.0f) * 1e-6f;
    }
}

// ================= optimized flash attention (r4-measured configuration) =====
#define KS_STR 136   /* 128 + 8 (bf16 elems); 8*odd for b128 bank spread */
#define VT_STR 72    /* 64 + 8 */
#define PE_STR 136
#define P_STR  72
#define T_STR  72

__global__ void __launch_bounds__(256, 2)
attn_kernel(const float* __restrict__ Q, const float* __restrict__ K,
            const float* __restrict__ V, const unsigned short* __restrict__ PET,
            const float* __restrict__ r0g, const float* __restrict__ tmax,
            float* __restrict__ out) {
    __shared__ short Ks[64 * KS_STR];        // K tile [l][d]
    __shared__ short Vt[128 * VT_STR];       // V tile transposed [d][l]
    __shared__ short PEs[64 * PE_STR];       // PE^T tile [c][d]
    __shared__ short Tb[2][64 * T_STR];      // rolling Q@PE tiles (wave-private rows)
    __shared__ short Pb[64 * P_STR];         // P tile [m][l] (wave-private rows)

    // XCD-contiguous remap (bijective, 512 = 8*64): each XCD gets 4 whole bh's
    // x all 16 i-blocks -> per-XCD K/V working set ~5.6MB, near L2-resident.
    const int flat = (int)blockIdx.x + 16 * (int)blockIdx.y;
    const int work = (flat & 7) * 64 + (flat >> 3);
    const int bh  = work >> 4;
    const int bxx = work & 15;
    const int b  = bh >> 3;
    const int i0 = bxx << 6;
    const int tid  = threadIdx.x;
    const int wave = tid >> 6;
    const int lane = tid & 63;
    const int lq   = lane & 15;
    const int quad = lane >> 4;
    const int lt_end = min(NT64, bxx + 35);   // causal bound

    // ---- live-tile bitmask: one ballot, no LDS, no barrier ----
    const float live_thresh = (float)(i0 - 128);
    unsigned long long live_mask;
    {
        const int sidx = (lane < NT64) ? lane : (NT64 - 1);
        const float tv = tmax[b * NT64 + sidx];
        live_mask = __ballot((lane < NT64) && (lane < lt_end) && (tv > live_thresh));
    }
    auto next_live = [&](int s) -> int {
        const unsigned long long m = live_mask >> s;   // s <= 50 < 64 always
        return m ? (s + __builtin_ctzll(m)) : lt_end;
    };

    // ---- prefetch registers (tile lt staged here before LDS write) ----
    float4 kp[8];
    float4 vpa[4], vpb[4];
    uint4  pep[4];
    float  rvp[4];            // per-lane r0 for cols nt*16+lq
    float  rv[4];             // current tile's r0 (copied at write_stage)

    auto issue_prefetch = [&](int plt) {
        const int l0p = plt << 6;
        const float* kb = K + ((size_t)bh * L_ + l0p) * D_;
        const float* vb = V + ((size_t)bh * L_ + l0p) * D_;
#pragma unroll
        for (int it = 0; it < 8; ++it) {
            const int f = it * 256 + tid;
            kp[it] = *(const float4*)(kb + (f >> 5) * D_ + (f & 31) * 4);
        }
        const int p2 = (tid & 31) * 2;
#pragma unroll
        for (int it = 0; it < 4; ++it) {
            const int c = it * 8 + (tid >> 5);
            vpa[it] = *(const float4*)(vb + (size_t)p2 * D_ + c * 4);
            vpb[it] = *(const float4*)(vb + (size_t)(p2 + 1) * D_ + c * 4);
        }
        const int c0p = l0p - i0 - POS_OFF;
#pragma unroll
        for (int it = 0; it < 4; ++it) {
            const int f = it * 256 + tid;
            const int cg = c0p + (f >> 4);
            if ((unsigned)cg < (unsigned)M_)
                pep[it] = *(const uint4*)(PET + (size_t)cg * D_ + (f & 15) * 8);
            else { pep[it].x = 0; pep[it].y = 0; pep[it].z = 0; pep[it].w = 0; }
        }
        const float* rb = r0g + b * L_ + l0p;
#pragma unroll
        for (int nt = 0; nt < 4; ++nt) rvp[nt] = rb[nt * 16 + lq];
    };

    auto write_stage = [&]() {
#pragma unroll
        for (int it = 0; it < 8; ++it) {
            const int f = it * 256 + tid;
            uint2 w;
            w.x = pack_bf2(kp[it].x, kp[it].y);
            w.y = pack_bf2(kp[it].z, kp[it].w);
            *(uint2*)&Ks[(f >> 5) * KS_STR + (f & 31) * 4] = w;
        }
        const int p2 = (tid & 31) * 2;
#pragma unroll
        for (int it = 0; it < 4; ++it) {
            const int c = it * 8 + (tid >> 5);
            const float* a = (const float*)&vpa[it];
            const float* bb = (const float*)&vpb[it];
#pragma unroll
            for (int j = 0; j < 4; ++j)
                *(uint32_t*)&Vt[(c * 4 + j) * VT_STR + p2] = pack_bf2(a[j], bb[j]);
        }
#pragma unroll
        for (int it = 0; it < 4; ++it) {
            const int f = it * 256 + tid;
            *(uint4*)&PEs[(f >> 4) * PE_STR + (f & 15) * 8] = pep[it];
        }
#pragma unroll
        for (int nt = 0; nt < 4; ++nt) rv[nt] = rvp[nt];
    };

    // ---- Q fragments ----
    int lt = next_live(0);
    if (lt < lt_end) issue_prefetch(lt);

    bf16x8 qfrag[4];
    {
        const float* qp = Q + ((size_t)bh * M_ + (i0 + wave * 16 + lq)) * D_;
#pragma unroll
        for (int kk = 0; kk < 4; ++kk) {
            const float4 q0 = *(const float4*)(qp + kk * 32 + quad * 8);
            const float4 q1 = *(const float4*)(qp + kk * 32 + quad * 8 + 4);
            union { bf16x8 v; uint32_t u[4]; } qq;
            qq.u[0] = pack_bf2(q0.x, q0.y); qq.u[1] = pack_bf2(q0.z, q0.w);
            qq.u[2] = pack_bf2(q1.x, q1.y); qq.u[3] = pack_bf2(q1.z, q1.w);
            qfrag[kk] = qq.v;
        }
    }

    auto computeT = [&](short* tb) {
        __builtin_amdgcn_s_setprio(1);
#pragma unroll
        for (int nt = 0; nt < 4; ++nt) {
            f32x4 acc = (f32x4){0.f, 0.f, 0.f, 0.f};
#pragma unroll
            for (int kk = 0; kk < 4; ++kk) {
                const bf16x8 bf = *(const bf16x8*)&PEs[(nt*16 + lq) * PE_STR + kk*32 + quad*8];
                acc = __builtin_amdgcn_mfma_f32_16x16x32_bf16(qfrag[kk], bf, acc, 0, 0, 0);
            }
#pragma unroll
            for (int r = 0; r < 4; ++r) {
                union { float f; uint32_t u; } t; t.f = acc[r];
                tb[(wave*16 + quad*4 + r) * T_STR + nt*16 + lq] = (short)(t.u >> 16);
            }
        }
        __builtin_amdgcn_s_setprio(0);
    };

    f32x4 oacc[8];
#pragma unroll
    for (int d = 0; d < 8; ++d) oacc[d] = (f32x4){0.f, 0.f, 0.f, 0.f};
    float mrun[4] = {NEGV, NEGV, NEGV, NEGV};
    float Zm[4]   = {0.f, 0.f, 0.f, 0.f};
    int tlo = 0, thi = 1;
    int prev_c0 = -(1 << 30);

    while (lt < lt_end) {
        const int l0 = lt << 6;
        const int c0 = l0 - i0 - POS_OFF;
        const bool need_pos = (c0 + 63 >= 0) && (c0 - 63 <= M_ - 1);
        const bool rolling  = need_pos && (prev_c0 == c0 - 64);

        __syncthreads();                       // sync0: prev LDS reads done; prefetch drained here
        write_stage();
        __syncthreads();                       // sync1: staging visible (no VMEM outstanding -> cheap)

        // issue NEXT tile's loads now — they overlap the whole compute phase
        const int ltn = next_live(lt + 1);
        if (ltn < lt_end) issue_prefetch(ltn);

        // S = Q @ K^T
        f32x4 sfrag[4];
        __builtin_amdgcn_s_setprio(1);
#pragma unroll
        for (int nt = 0; nt < 4; ++nt) {
            f32x4 acc = (f32x4){0.f, 0.f, 0.f, 0.f};
#pragma unroll
            for (int kk = 0; kk < 4; ++kk) {
                const bf16x8 bf = *(const bf16x8*)&Ks[(nt*16 + lq) * KS_STR + kk*32 + quad*8];
                acc = __builtin_amdgcn_mfma_f32_16x16x32_bf16(qfrag[kk], bf, acc, 0, 0, 0);
            }
            sfrag[nt] = acc;
        }
        __builtin_amdgcn_s_setprio(0);

        // rel-pos T tiles (Tb rows are wave-private: no barrier needed)
        if (need_pos) {
            if (rolling) {
                const int t = tlo; tlo = thi; thi = t;
                computeT(&Tb[thi][0]);
            } else {
                tlo = 0; thi = 1;
                computeT(&Tb[1][0]);
                // restage PEs with the low tile (head/gap only, ~once per block)
                uint4 lowp[4];
#pragma unroll
                for (int it = 0; it < 4; ++it) {
                    const int f = it * 256 + tid;
                    const int cg = (c0 - 64) + (f >> 4);
                    if ((unsigned)cg < (unsigned)M_)
                        lowp[it] = *(const uint4*)(PET + (size_t)cg * D_ + (f & 15) * 8);
                    else { lowp[it].x = 0; lowp[it].y = 0; lowp[it].z = 0; lowp[it].w = 0; }
                }
                __syncthreads();               // all waves done reading PEs (T-hi)
#pragma unroll
                for (int it = 0; it < 4; ++it) {
                    const int f = it * 256 + tid;
                    *(uint4*)&PEs[(f >> 4) * PE_STR + (f & 15) * 8] = lowp[it];
                }
                __syncthreads();
                computeT(&Tb[0][0]);
            }
            prev_c0 = c0;
        } else {
            prev_c0 = -(1 << 30);
        }

        // fused mask + online softmax, one pass per row (sv/ev transient ->
        // minimal live set; this is the spill-free r4 configuration)
#pragma unroll
        for (int r = 0; r < 4; ++r) {
            const int iq = i0 + wave*16 + quad*4 + r;
            const float fiq = (float)iq;
            float sv[4], ev[4];
#pragma unroll
            for (int nt = 0; nt < 4; ++nt) {
                const int l = l0 + nt*16 + lq;
                float s = sfrag[nt][r];
                const int c = l - iq - POS_OFF;
                if (need_pos && (unsigned)c < (unsigned)M_) {
                    const int cb = c - (c0 - 64);          // in [1,127]
                    const short* tbp = (cb & 64) ? &Tb[thi][0] : &Tb[tlo][0];
                    s += bf2f((unsigned short)tbp[(wave*16 + quad*4 + r) * T_STR + (cb & 63)]);
                }
                const float e = fminf(fmaxf((rv[nt] - fiq) * 0.0078125f + 1.0f, 0.f), 1.f);
                ev[nt] = e;
                const bool live = (l <= iq + CAUSAL_K) && (e > 0.f);
                sv[nt] = live ? s * SCALE : NEGV;
            }
            float v = fmaxf(fmaxf(sv[0], sv[1]), fmaxf(sv[2], sv[3]));
            v = row_max16(v);
            const float nm = fmaxf(mrun[r], v);
            float alpha = 1.f, pmsum = 0.f, pmv[4];
            if (nm > NEGH) {
                alpha = (mrun[r] > NEGH) ? __expf(mrun[r] - nm) : 0.f;
#pragma unroll
                for (int nt = 0; nt < 4; ++nt) {
                    const float p = __expf(sv[nt] - nm);   // dead -> 0
                    const float pm = p * ev[nt];
                    pmsum += pm; pmv[nt] = pm;
                }
            } else {
                pmv[0] = pmv[1] = pmv[2] = pmv[3] = 0.f;
            }
            pmsum = row_sum16(pmsum);
            mrun[r] = nm;
            Zm[r] = Zm[r] * alpha + pmsum;
#pragma unroll
            for (int d = 0; d < 8; ++d) oacc[d][r] *= alpha;
#pragma unroll
            for (int nt = 0; nt < 4; ++nt) {
                union { float f; uint32_t u; } t; t.f = pmv[nt];
                Pb[(wave*16 + quad*4 + r) * P_STR + nt*16 + lq] = (short)(t.u >> 16);
            }
        }
        // no barrier: Pb rows are wave-private (writer rows wave*16+quad*4+r,
        // reader rows wave*16+lq are the same 16-row strip)

        // O += P @ V
        __builtin_amdgcn_s_setprio(1);
#pragma unroll
        for (int kk = 0; kk < 2; ++kk) {
            const bf16x8 pf = *(const bf16x8*)&Pb[(wave*16 + lq) * P_STR + kk*32 + quad*8];
#pragma unroll
            for (int dt = 0; dt < 8; ++dt) {
                const bf16x8 vf = *(const bf16x8*)&Vt[(dt*16 + lq) * VT_STR + kk*32 + quad*8];
                oacc[dt] = __builtin_amdgcn_mfma_f32_16x16x32_bf16(pf, vf, oacc[dt], 0, 0, 0);
            }
        }
        __builtin_amdgcn_s_setprio(0);
        lt = ltn;
    }

    // epilogue: out = O / (Zm + 1e-8)
#pragma unroll
    for (int r = 0; r < 4; ++r) {
        const int iq = i0 + wave*16 + quad*4 + r;
        const float inv = 1.0f / (Zm[r] + 1e-8f);
        float* op = out + ((size_t)bh * M_ + iq) * D_;
#pragma unroll
        for (int dt = 0; dt < 8; ++dt)
            op[dt*16 + lq] = oacc[dt][r] * inv;
    }
}

// ================= fallback (only if ws too small for PET) =================
__global__ void __launch_bounds__(256, 2)
attn_fb_kernel(const float* __restrict__ Q, const float* __restrict__ K,
               const float* __restrict__ V, const float* __restrict__ PE,
               const float* __restrict__ r0g, const float* __restrict__ tmax,
               float* __restrict__ out) {
    __shared__ short Ks[64 * KS_STR];
    __shared__ short Vt[128 * VT_STR];
    __shared__ short PEP[64 * PE_STR];
    __shared__ short Tb[2][64 * T_STR];
    __shared__ float r0s[64];

    const int bh = blockIdx.y;
    const int b  = bh >> 3;
    const int i0 = blockIdx.x << 6;
    const int tid  = threadIdx.x;
    const int wave = tid >> 6;
    const int lane = tid & 63;
    const int lq   = lane & 15;
    const int quad = lane >> 4;

    bf16x8 qfrag[4];
    {
        const float* qp = Q + ((size_t)bh * M_ + (i0 + wave * 16 + lq)) * D_;
#pragma unroll
        for (int kk = 0; kk < 4; ++kk) {
            const float* p = qp + kk * 32 + quad * 8;
            bf16x8 f;
#pragma unroll
            for (int j = 0; j < 8; ++j) f[j] = (short)f2bf(p[j]);
            qfrag[kk] = f;
        }
    }

    f32x4 oacc[8];
#pragma unroll
    for (int d = 0; d < 8; ++d) oacc[d] = (f32x4){0.f, 0.f, 0.f, 0.f};
    float mrun[4] = {NEGV, NEGV, NEGV, NEGV};
    float Zr[4]   = {0.f, 0.f, 0.f, 0.f};
    float Zm[4]   = {0.f, 0.f, 0.f, 0.f};

    int tlo = 0, thi = 1;
    int prev_c0 = -100000;

    auto stagePE = [&](int cbase) {
#pragma unroll
        for (int it = 0; it < 8; ++it) {
            const int f4 = it * 256 + tid;
            const int d  = f4 >> 4;
            const int cl = (f4 & 15) << 2;
#pragma unroll
            for (int j = 0; j < 4; ++j) {
                const int cg = cbase + cl + j;
                const float v = (cg >= 0 && cg < M_) ? PE[d * M_ + cg] : 0.f;
                PEP[(cl + j) * PE_STR + d] = (short)f2bf(v);
            }
        }
    };
    auto computeT = [&](short* tb) {
#pragma unroll
        for (int nt = 0; nt < 4; ++nt) {
            f32x4 acc = (f32x4){0.f, 0.f, 0.f, 0.f};
#pragma unroll
            for (int kk = 0; kk < 4; ++kk) {
                const bf16x8 bf = *(const bf16x8*)&PEP[(nt*16 + lq) * PE_STR + kk*32 + quad*8];
                acc = __builtin_amdgcn_mfma_f32_16x16x32_bf16(qfrag[kk], bf, acc, 0, 0, 0);
            }
#pragma unroll
            for (int r = 0; r < 4; ++r)
                tb[(wave*16 + quad*4 + r) * T_STR + nt*16 + lq] = (short)f2bf(acc[r]);
        }
    };

    const int lt_end = min(NT64, (int)blockIdx.x + 35);
    for (int lt = 0; lt < lt_end; ++lt) {
        const int l0 = lt << 6;
        if (!(tmax[b * NT64 + lt] > (float)(i0 - 128))) continue;

        __syncthreads();
        {
            const float* kbase = K + ((size_t)bh * L_ + l0) * D_;
            const float* vbase = V + ((size_t)bh * L_ + l0) * D_;
#pragma unroll
            for (int it = 0; it < 8; ++it) {
                const int f4 = it * 256 + tid;
                const int row = f4 >> 5;
                const int ds  = (f4 & 31) << 2;
                const float4 kv = *(const float4*)(kbase + row * D_ + ds);
                uint2 pk;
                pk.x = (uint32_t)f2bf(kv.x) | ((uint32_t)f2bf(kv.y) << 16);
                pk.y = (uint32_t)f2bf(kv.z) | ((uint32_t)f2bf(kv.w) << 16);
                *(uint2*)&Ks[row * KS_STR + ds] = pk;
                const float4 vv = *(const float4*)(vbase + row * D_ + ds);
                Vt[(ds+0) * VT_STR + row] = (short)f2bf(vv.x);
                Vt[(ds+1) * VT_STR + row] = (short)f2bf(vv.y);
                Vt[(ds+2) * VT_STR + row] = (short)f2bf(vv.z);
                Vt[(ds+3) * VT_STR + row] = (short)f2bf(vv.w);
            }
            if (tid < 64) r0s[tid] = r0g[b * L_ + l0 + tid];
        }

        const int c0 = l0 - i0 - POS_OFF;
        const bool need_pos = (c0 + 63 >= 0) && (c0 - 63 <= M_ - 1);
        if (need_pos) {
            if (prev_c0 == c0 - 64) {
                const int t = tlo; tlo = thi; thi = t;
                stagePE(c0);
                __syncthreads();
                computeT(&Tb[thi][0]);
            } else {
                stagePE(c0 - 64);
                __syncthreads();
                computeT(&Tb[0][0]);
                __syncthreads();
                stagePE(c0);
                __syncthreads();
                computeT(&Tb[1][0]);
                tlo = 0; thi = 1;
            }
            prev_c0 = c0;
        } else {
            __syncthreads();
        }

        f32x4 sfrag[4];
#pragma unroll
        for (int nt = 0; nt < 4; ++nt) {
            f32x4 acc = (f32x4){0.f, 0.f, 0.f, 0.f};
#pragma unroll
            for (int kk = 0; kk < 4; ++kk) {
                const bf16x8 bf = *(const bf16x8*)&Ks[(nt*16 + lq) * KS_STR + kk*32 + quad*8];
                acc = __builtin_amdgcn_mfma_f32_16x16x32_bf16(qfrag[kk], bf, acc, 0, 0, 0);
            }
            sfrag[nt] = acc;
        }
        __syncthreads();

        float sv[4][4];
#pragma unroll
        for (int r = 0; r < 4; ++r) {
            const int iq = i0 + wave*16 + quad*4 + r;
#pragma unroll
            for (int nt = 0; nt < 4; ++nt) {
                const int l = l0 + nt*16 + lq;
                float s = sfrag[nt][r];
                const int c = l - iq - POS_OFF;
                if (c >= 0 && c < M_) {
                    const int cb = c - (c0 - 64);
                    const short* tbp = (cb & 64) ? &Tb[thi][0] : &Tb[tlo][0];
                    s += bf2f((unsigned short)tbp[(wave*16 + quad*4 + r) * T_STR + (cb & 63)]);
                }
                const float e = fminf(fmaxf((r0s[nt*16 + lq] - (float)iq) * 0.0078125f + 1.0f, 0.f), 1.f);
                const bool live = (l <= iq + CAUSAL_K) && (e > 0.f);
                sv[r][nt] = live ? s * SCALE : NEGV;
            }
        }

#pragma unroll
        for (int r = 0; r < 4; ++r) {
            float v = fmaxf(fmaxf(sv[r][0], sv[r][1]), fmaxf(sv[r][2], sv[r][3]));
            v = row_max16(v);
            const float nm = fmaxf(mrun[r], v);
            float alpha, pmv[4];
            float psum = 0.f, pmsum = 0.f;
            if (nm > NEGH) {
                alpha = (mrun[r] > NEGH) ? __expf(mrun[r] - nm) : 0.f;
                const int iq = i0 + wave*16 + quad*4 + r;
#pragma unroll
                for (int nt = 0; nt < 4; ++nt) {
                    const float p = __expf(sv[r][nt] - nm);
                    const float e = fminf(fmaxf((r0s[nt*16 + lq] - (float)iq) * 0.0078125f + 1.0f, 0.f), 1.f);
                    const float pm = p * e;
                    psum += p; pmsum += pm; pmv[nt] = pm;
                }
            } else {
                alpha = 1.f;
                pmv[0] = pmv[1] = pmv[2] = pmv[3] = 0.f;
            }
            psum  = row_sum16(psum);
            pmsum = row_sum16(pmsum);
            mrun[r] = nm;
            Zr[r] = Zr[r] * alpha + psum;
            Zm[r] = Zm[r] * alpha + pmsum;
#pragma unroll
            for (int d = 0; d < 8; ++d) oacc[d][r] *= alpha;
#pragma unroll
            for (int nt = 0; nt < 4; ++nt)
                PEP[(wave*16 + quad*4 + r) * P_STR + nt*16 + lq] = (short)f2bf(pmv[nt]);
        }
        __syncthreads();

#pragma unroll
        for (int kk = 0; kk < 2; ++kk) {
            const bf16x8 pf = *(const bf16x8*)&PEP[(wave*16 + lq) * P_STR + kk*32 + quad*8];
#pragma unroll
            for (int dt = 0; dt < 8; ++dt) {
                const bf16x8 vf = *(const bf16x8*)&Vt[(dt*16 + lq) * VT_STR + kk*32 + quad*8];
                oacc[dt] = __builtin_amdgcn_mfma_f32_16x16x32_bf16(pf, vf, oacc[dt], 0, 0, 0);
            }
        }
    }

#pragma unroll
    for (int r = 0; r < 4; ++r) {
        const int iq = i0 + wave*16 + quad*4 + r;
        const float inv = 1.0f / (Zm[r] + 1e-8f * Zr[r]);
        float* op = out + ((size_t)bh * M_ + iq) * D_;
#pragma unroll
        for (int dt = 0; dt < 8; ++dt)
            op[dt*16 + lq] = oacc[dt][r] * inv;
    }
}

extern "C" void kernel_launch(void* const* d_in, const int* in_sizes, int n_in,
                              void* d_out, int out_size, void* d_ws, size_t ws_size,
                              hipStream_t stream) {
    (void)in_sizes; (void)n_in; (void)out_size;
    const float* Q       = (const float*)d_in[0];
    const float* K       = (const float*)d_in[1];
    const float* V       = (const float*)d_in[2];
    const float* hid     = (const float*)d_in[3];
    const float* counter = (const float*)d_in[4];
    const float* pe      = (const float*)d_in[5];
    const float* sw      = (const float*)d_in[6];
    const float* sb      = (const float*)d_in[7];

    float* out    = (float*)d_out;
    float* aux    = out + (size_t)BH_ * M_ * D_;
    float* r0_out = aux + B_;

    float* r0_ws = (float*)d_ws;                         // 12800 floats
    float* tmax  = r0_ws + B_ * L_;                      // 200 floats
    unsigned short* PET = (unsigned short*)(r0_ws + 13056); // 1024*128 bf16, 16B-aligned
    const bool use_pet = ws_size >= (size_t)(13056 * 4 + M_ * D_ * 2);

    span_pet_kernel<<<(B_ * L_) / 4, 256, 0, stream>>>(
        hid, counter, sw, sb, pe, r0_ws, r0_out, use_pet ? PET : nullptr);
    prep_kernel<<<54, 256, 0, stream>>>(r0_ws, tmax, aux);
    if (use_pet) {
        attn_kernel<<<dim3(M_ / 64, BH_), 256, 0, stream>>>(Q, K, V, PET, r0_ws, tmax, out);
    } else {
        attn_fb_kernel<<<dim3(M_ / 64, BH_), 256, 0, stream>>>(Q, K, V, pe, r0_ws, tmax, out);
    }
}